// Round 1
// baseline (316.379 us; speedup 1.0000x reference)
//
#include <hip/hip_runtime.h>

typedef __bf16 bf16x8 __attribute__((ext_vector_type(8)));
typedef __bf16 bf16x4 __attribute__((ext_vector_type(4)));
typedef float  f32x16 __attribute__((ext_vector_type(16)));

#define LOG2E 1.4426950408889634f

__device__ __forceinline__ float fexp2(float x) { return __builtin_amdgcn_exp2f(x); }
__device__ __forceinline__ float frcp(float x)  { return __builtin_amdgcn_rcpf(x); }
__device__ __forceinline__ float fsigmoid(float x) { return frcp(1.0f + fexp2(-LOG2E * x)); }
__device__ __forceinline__ float ftanh(float x)    { return 2.0f * frcp(1.0f + fexp2(-2.0f * LOG2E * x)) - 1.0f; }

// ---------------------------------------------------------------------------
// Prep: convert 4 [512x512] fp32 weight matrices to bf16 into ws as [4][512][512]
// (row-major per gate; W[j][k] layout == MFMA B-fragment wants 8 contiguous k per col j)
// ---------------------------------------------------------------------------
__global__ __launch_bounds__(256) void wcvt(const float* __restrict__ Wf,
                                            const float* __restrict__ Wi,
                                            const float* __restrict__ Wg,
                                            const float* __restrict__ Wo,
                                            __bf16* __restrict__ W4)
{
    int idx = blockIdx.x * 256 + threadIdx.x;      // float4 index, 262144 total
    int g   = idx >> 16;                           // 65536 float4 per matrix
    int rem = idx & 65535;
    const float* src = (g == 0) ? Wf : (g == 1) ? Wi : (g == 2) ? Wg : Wo;
    float4 v = ((const float4*)src)[rem];
    bf16x4 o;
    o[0] = (__bf16)v.x; o[1] = (__bf16)v.y; o[2] = (__bf16)v.z; o[3] = (__bf16)v.w;
    *(bf16x4*)(W4 + (size_t)idx * 4) = o;
}

// ---------------------------------------------------------------------------
// Main fused kernel: z = x+stm (bf16, LDS), 4-gate MFMA GEMM, activation epilogue
// Block: 256 thr (4 waves), 64 rows. Wave w owns cols [ci*128 + w*32, +32) per iter.
// ---------------------------------------------------------------------------
__global__ __launch_bounds__(256, 2) void lstm_main(
    const float* __restrict__ xin, const float* __restrict__ stm,
    const __bf16* __restrict__ W4,
    const float* __restrict__ bfv, const float* __restrict__ biv,
    const float* __restrict__ bgv, const float* __restrict__ bov,
    float* __restrict__ out)
{
    __shared__ unsigned char zs[64 * 512 * 2];     // 64 KiB z-tile, bf16, swizzled
    const int tid  = threadIdx.x;
    const int lane = tid & 63;
    const int wv   = tid >> 6;                     // 0..3 column-group
    const int l31  = lane & 31;
    const int hi   = lane >> 5;
    const int row0 = blockIdx.x * 64;

    // ---- phase 0: z = x + stm -> bf16 -> LDS (XOR-swizzled rows) ----
    {
        const float4* xin4 = (const float4*)(xin + (size_t)row0 * 512);
        const float4* stm4 = (const float4*)(stm + (size_t)row0 * 512);
        #pragma unroll 4
        for (int it = 0; it < 32; ++it) {
            int f4 = it * 256 + tid;               // 8192 float4 per tile
            float4 a = xin4[f4];
            float4 b = stm4[f4];
            bf16x4 p;
            p[0] = (__bf16)(a.x + b.x);
            p[1] = (__bf16)(a.y + b.y);
            p[2] = (__bf16)(a.z + b.z);
            p[3] = (__bf16)(a.w + b.w);
            int row  = f4 >> 7;                    // 128 float4 per row
            int col4 = f4 & 127;
            int byte = row * 1024 + col4 * 8;
            byte ^= (row & 7) << 4;                // bank-conflict swizzle
            *(bf16x4*)(zs + byte) = p;
        }
    }
    __syncthreads();                               // only barrier in the kernel

    // ---- phase 1: column loop, no barriers (z LDS is read-only now) ----
    for (int ci = 0; ci < 4; ++ci) {
        const int colB = ci * 128 + wv * 32;
        const int colj = colB + l31;

        // B-fragment base pointers (gate-major bf16 weights, L2-resident)
        const __bf16* bp0 = W4 + ((size_t)(       colj)) * 512 + hi * 8;
        const __bf16* bp1 = W4 + ((size_t)( 512 + colj)) * 512 + hi * 8;
        const __bf16* bp2 = W4 + ((size_t)(1024 + colj)) * 512 + hi * 8;
        const __bf16* bp3 = W4 + ((size_t)(1536 + colj)) * 512 + hi * 8;

        // bias folded into accumulator init (bias depends only on col)
        float bias0 = bfv[colj], bias1 = biv[colj], bias2 = bgv[colj], bias3 = bov[colj];
        f32x16 acc[2][4];
        #pragma unroll
        for (int m = 0; m < 2; ++m) {
            #pragma unroll
            for (int r = 0; r < 16; ++r) {
                acc[m][0][r] = bias0; acc[m][1][r] = bias1;
                acc[m][2][r] = bias2; acc[m][3][r] = bias3;
            }
        }

        const int arow0 = l31;          // M-frag 0 rows
        const int arow1 = 32 + l31;     // M-frag 1 rows
        const int sw0 = (arow0 & 7) << 4;
        const int sw1 = (arow1 & 7) << 4;
        const int ab0 = arow0 * 1024 + hi * 16;
        const int ab1 = arow1 * 1024 + hi * 16;

        #pragma unroll 4
        for (int kk = 0; kk < 32; ++kk) {
            int ko = kk * 32;           // byte step: 16 k-elems * 2B
            bf16x8 a0 = *(const bf16x8*)(zs + ((ab0 + ko) ^ sw0));
            bf16x8 a1 = *(const bf16x8*)(zs + ((ab1 + ko) ^ sw1));
            bf16x8 b0 = *(const bf16x8*)(bp0 + kk * 16);
            bf16x8 b1 = *(const bf16x8*)(bp1 + kk * 16);
            bf16x8 b2 = *(const bf16x8*)(bp2 + kk * 16);
            bf16x8 b3 = *(const bf16x8*)(bp3 + kk * 16);
            acc[0][0] = __builtin_amdgcn_mfma_f32_32x32x16_bf16(a0, b0, acc[0][0], 0, 0, 0);
            acc[1][0] = __builtin_amdgcn_mfma_f32_32x32x16_bf16(a1, b0, acc[1][0], 0, 0, 0);
            acc[0][1] = __builtin_amdgcn_mfma_f32_32x32x16_bf16(a0, b1, acc[0][1], 0, 0, 0);
            acc[1][1] = __builtin_amdgcn_mfma_f32_32x32x16_bf16(a1, b1, acc[1][1], 0, 0, 0);
            acc[0][2] = __builtin_amdgcn_mfma_f32_32x32x16_bf16(a0, b2, acc[0][2], 0, 0, 0);
            acc[1][2] = __builtin_amdgcn_mfma_f32_32x32x16_bf16(a1, b2, acc[1][2], 0, 0, 0);
            acc[0][3] = __builtin_amdgcn_mfma_f32_32x32x16_bf16(a0, b3, acc[0][3], 0, 0, 0);
            acc[1][3] = __builtin_amdgcn_mfma_f32_32x32x16_bf16(a1, b3, acc[1][3], 0, 0, 0);
        }

        // ---- epilogue: gates -> c,h and store (C/D layout: col=l&31, row=(r&3)+8*(r>>2)+4*hi) ----
        #pragma unroll
        for (int m = 0; m < 2; ++m) {
            #pragma unroll
            for (int r = 0; r < 16; ++r) {
                float F = acc[m][0][r], I = acc[m][1][r];
                float G = acc[m][2][r], O = acc[m][3][r];
                float c = fsigmoid(F) + fsigmoid(I) * ftanh(G);
                float h = ftanh(c) * fsigmoid(O);
                int row = row0 + m * 32 + (r & 3) + 8 * (r >> 2) + 4 * hi;
                int o   = row * 512 + colB + l31;
                out[o] = c;
                out[33554432 + o] = h;   // 65536*512 offset: h plane
            }
        }
    }
}

extern "C" void kernel_launch(void* const* d_in, const int* in_sizes, int n_in,
                              void* d_out, int out_size, void* d_ws, size_t ws_size,
                              hipStream_t stream) {
    const float* xin = (const float*)d_in[0];
    const float* stm = (const float*)d_in[1];
    const float* Wf  = (const float*)d_in[2];
    const float* bf_ = (const float*)d_in[3];
    const float* Wi  = (const float*)d_in[4];
    const float* bi_ = (const float*)d_in[5];
    const float* Wg  = (const float*)d_in[6];
    const float* bg_ = (const float*)d_in[7];
    const float* Wo  = (const float*)d_in[8];
    const float* bo_ = (const float*)d_in[9];
    __bf16* W4 = (__bf16*)d_ws;                    // 4*512*512*2 = 2 MiB scratch

    wcvt<<<1024, 256, 0, stream>>>(Wf, Wi, Wg, Wo, W4);
    lstm_main<<<1024, 256, 0, stream>>>(xin, stm, W4, bf_, bi_, bg_, bo_, (float*)d_out);
}

// Round 2
// 257.697 us; speedup vs baseline: 1.2277x; 1.2277x over previous
//
#include <hip/hip_runtime.h>

typedef __bf16 bf16x8 __attribute__((ext_vector_type(8)));
typedef float  f32x16 __attribute__((ext_vector_type(16)));

#define LOG2E 1.4426950408889634f

static __device__ __forceinline__ float fexp2(float x) { return __builtin_amdgcn_exp2f(x); }
static __device__ __forceinline__ float frcp(float x)  { return __builtin_amdgcn_rcpf(x); }
static __device__ __forceinline__ float fsigmoid(float x) { return frcp(1.0f + fexp2(-LOG2E * x)); }
static __device__ __forceinline__ float ftanh(float x)    { return 2.0f * frcp(1.0f + fexp2(-2.0f * LOG2E * x)) - 1.0f; }

// ---------------------------------------------------------------------------
// Prep: pack 4 [512x512] fp32 weights into bf16 MFMA-B-fragment-coalesced layout.
// Wp[((g*16+cb)*32+kk)*512 + lane*8 + e] = W_g[cb*32+(lane&31)][kk*16+(lane>>5)*8+e]
// so a wave's per-kk B load is base + kk*1024B + lane*16B (fully coalesced 1 KiB).
// ---------------------------------------------------------------------------
__global__ __launch_bounds__(256) void wpack(const float* __restrict__ Wf,
                                             const float* __restrict__ Wi,
                                             const float* __restrict__ Wg,
                                             const float* __restrict__ Wo,
                                             __bf16* __restrict__ Wp)
{
    int idx = blockIdx.x * 256 + threadIdx.x;      // [0, 131072)
    int kg  = idx & 63;                            // k-group of 8
    int j   = (idx >> 6) & 511;                    // weight row = output col
    int g   = idx >> 15;
    const float* src = (g == 0) ? Wf : (g == 1) ? Wi : (g == 2) ? Wg : Wo;
    const float4* s4 = (const float4*)(src + j * 512 + kg * 8);
    float4 v0 = s4[0], v1 = s4[1];
    bf16x8 o;
    o[0] = (__bf16)v0.x; o[1] = (__bf16)v0.y; o[2] = (__bf16)v0.z; o[3] = (__bf16)v0.w;
    o[4] = (__bf16)v1.x; o[5] = (__bf16)v1.y; o[6] = (__bf16)v1.z; o[7] = (__bf16)v1.w;
    int cb = j >> 5;
    int kk = kg >> 1;
    int lane_t = (j & 31) + (kg & 1) * 32;
    size_t dst = ((size_t)((g * 16 + cb) * 32 + kk)) * 512 + lane_t * 8;
    *(bf16x8*)(Wp + dst) = o;
}

// ---------------------------------------------------------------------------
// Main fused kernel. Block: 256 thr (4 waves), 64 rows.
// LDS holds z in A-fragment order: chunk(rb,kk) = 1024B, slot = lane^(kk&7),
// slot holds z[rb*32+(lane&31)][kk*16+(lane>>5)*8 + 0..7].
// Reads: ds_read_b128 at kk*1024 + (lane*16 ^ ((kk&7)<<4)) -> conflict-free.
// ---------------------------------------------------------------------------
__global__ __launch_bounds__(256, 2) void lstm_main(
    const float* __restrict__ xin, const float* __restrict__ stm,
    const __bf16* __restrict__ Wp,
    const float* __restrict__ bfv, const float* __restrict__ biv,
    const float* __restrict__ bgv, const float* __restrict__ bov,
    float* __restrict__ out)
{
    __shared__ unsigned char zs[65536];            // 64 rows x 512 k, bf16, frag order
    const int tid  = threadIdx.x;
    const int lane = tid & 63;
    const int wv   = tid >> 6;                     // 0..3
    const int l31  = lane & 31;
    const int hi   = lane >> 5;
    const int row0 = blockIdx.x * 64;

    // ---- phase 0: z = x + stm -> bf16 -> LDS in fragment order ----
    {
        const float* xb = xin + (size_t)row0 * 512;
        const float* sb = stm + (size_t)row0 * 512;
        #pragma unroll
        for (int it = 0; it < 16; ++it) {
            int idx = it * 256 + tid;              // [0, 4096): 64 rows x 64 kgroups
            int row = idx >> 6;
            int kg  = idx & 63;
            const float4* x4 = (const float4*)(xb + row * 512 + kg * 8);
            const float4* s4 = (const float4*)(sb + row * 512 + kg * 8);
            float4 a0 = x4[0], a1 = x4[1];
            float4 b0 = s4[0], b1 = s4[1];
            bf16x8 p;
            p[0] = (__bf16)(a0.x + b0.x); p[1] = (__bf16)(a0.y + b0.y);
            p[2] = (__bf16)(a0.z + b0.z); p[3] = (__bf16)(a0.w + b0.w);
            p[4] = (__bf16)(a1.x + b1.x); p[5] = (__bf16)(a1.y + b1.y);
            p[6] = (__bf16)(a1.z + b1.z); p[7] = (__bf16)(a1.w + b1.w);
            int rb   = row >> 5;
            int kk   = kg >> 1;
            int slot = ((row & 31) + (kg & 1) * 32) ^ (kk & 7);
            *(bf16x8*)(zs + rb * 32768 + kk * 1024 + slot * 16) = p;
        }
    }
    __syncthreads();                               // only barrier

    const int lane16 = lane * 16;

    // ---- phase 1: column loop, no barriers ----
    for (int ci = 0; ci < 4; ++ci) {
        const int cb   = ci * 4 + wv;
        const int colB = cb * 32;
        const int colj = colB + l31;

        const __bf16* bp0 = Wp + ((size_t)(( 0 + cb) * 32)) * 512 + lane * 8;
        const __bf16* bp1 = Wp + ((size_t)((16 + cb) * 32)) * 512 + lane * 8;
        const __bf16* bp2 = Wp + ((size_t)((32 + cb) * 32)) * 512 + lane * 8;
        const __bf16* bp3 = Wp + ((size_t)((48 + cb) * 32)) * 512 + lane * 8;

        float bias0 = bfv[colj], bias1 = biv[colj], bias2 = bgv[colj], bias3 = bov[colj];
        f32x16 acc[2][4];
        #pragma unroll
        for (int m = 0; m < 2; ++m) {
            #pragma unroll
            for (int r = 0; r < 16; ++r) {
                acc[m][0][r] = bias0; acc[m][1][r] = bias1;
                acc[m][2][r] = bias2; acc[m][3][r] = bias3;
            }
        }

        #pragma unroll 8
        for (int kk = 0; kk < 32; ++kk) {
            const int asw = (kk & 7) << 4;
            bf16x8 a0 = *(const bf16x8*)(zs +         kk * 1024 + (lane16 ^ asw));
            bf16x8 a1 = *(const bf16x8*)(zs + 32768 + kk * 1024 + (lane16 ^ asw));
            bf16x8 b0 = *(const bf16x8*)(bp0 + kk * 512);
            bf16x8 b1 = *(const bf16x8*)(bp1 + kk * 512);
            bf16x8 b2 = *(const bf16x8*)(bp2 + kk * 512);
            bf16x8 b3 = *(const bf16x8*)(bp3 + kk * 512);
            acc[0][0] = __builtin_amdgcn_mfma_f32_32x32x16_bf16(a0, b0, acc[0][0], 0, 0, 0);
            acc[1][0] = __builtin_amdgcn_mfma_f32_32x32x16_bf16(a1, b0, acc[1][0], 0, 0, 0);
            acc[0][1] = __builtin_amdgcn_mfma_f32_32x32x16_bf16(a0, b1, acc[0][1], 0, 0, 0);
            acc[1][1] = __builtin_amdgcn_mfma_f32_32x32x16_bf16(a1, b1, acc[1][1], 0, 0, 0);
            acc[0][2] = __builtin_amdgcn_mfma_f32_32x32x16_bf16(a0, b2, acc[0][2], 0, 0, 0);
            acc[1][2] = __builtin_amdgcn_mfma_f32_32x32x16_bf16(a1, b2, acc[1][2], 0, 0, 0);
            acc[0][3] = __builtin_amdgcn_mfma_f32_32x32x16_bf16(a0, b3, acc[0][3], 0, 0, 0);
            acc[1][3] = __builtin_amdgcn_mfma_f32_32x32x16_bf16(a1, b3, acc[1][3], 0, 0, 0);
        }

        // ---- epilogue: C/D layout col=l&31, row=(r&3)+8*(r>>2)+4*hi ----
        #pragma unroll
        for (int m = 0; m < 2; ++m) {
            #pragma unroll
            for (int r = 0; r < 16; ++r) {
                float F = acc[m][0][r], I = acc[m][1][r];
                float G = acc[m][2][r], O = acc[m][3][r];
                float c = fsigmoid(F) + fsigmoid(I) * ftanh(G);
                float h = ftanh(c) * fsigmoid(O);
                int row = row0 + m * 32 + (r & 3) + 8 * (r >> 2) + 4 * hi;
                int o   = row * 512 + colj;
                out[o] = c;
                out[33554432 + o] = h;             // h plane at 65536*512
            }
        }
    }
}

extern "C" void kernel_launch(void* const* d_in, const int* in_sizes, int n_in,
                              void* d_out, int out_size, void* d_ws, size_t ws_size,
                              hipStream_t stream) {
    const float* xin = (const float*)d_in[0];
    const float* stm = (const float*)d_in[1];
    const float* Wf  = (const float*)d_in[2];
    const float* bf_ = (const float*)d_in[3];
    const float* Wi  = (const float*)d_in[4];
    const float* bi_ = (const float*)d_in[5];
    const float* Wg  = (const float*)d_in[6];
    const float* bg_ = (const float*)d_in[7];
    const float* Wo  = (const float*)d_in[8];
    const float* bo_ = (const float*)d_in[9];
    __bf16* Wp = (__bf16*)d_ws;                    // 2 MiB packed weights

    wpack<<<512, 256, 0, stream>>>(Wf, Wi, Wg, Wo, Wp);
    lstm_main<<<1024, 256, 0, stream>>>(xin, stm, Wp, bf_, bi_, bg_, bo_, (float*)d_out);
}